// Round 6
// baseline (280.881 us; speedup 1.0000x reference)
//
#include <hip/hip_runtime.h>
#include <cstdint>
#include <cstddef>

#define S_DIM 1024
#define NPTS (S_DIM * S_DIM)
#define NLEV 16
#define TBL (1u << 19)
#define TMASK (TBL - 1u)
#define PRIME_Y 2654435761u

typedef float v4f __attribute__((ext_vector_type(4)));
typedef short v8s __attribute__((ext_vector_type(8)));

// ---- split-bf16 helpers: x = hi + lo, both truncated bf16 ----
// pack two fp32 (a=even k, b=odd k) into one dword of 2 bf16 (a in low short).
__device__ __forceinline__ void split2(float a, float b, uint32_t& hi, uint32_t& lo) {
    uint32_t ua = __float_as_uint(a), ub = __float_as_uint(b);
    uint32_t ha = ua & 0xFFFF0000u, hb = ub & 0xFFFF0000u;
    float la = a - __uint_as_float(ha);
    float lb = b - __uint_as_float(hb);
    hi = (ha >> 16) | hb;
    lo = (__float_as_uint(la) >> 16) | (__float_as_uint(lb) & 0xFFFF0000u);
}

// ============================================================================
// Pre-pass (verified round 5): bf16 hi/lo A-fragments of W0^T (64x32) and
// W1^T (64x64), fragment-linear in d_ws.
// ws as uint4: [0,256) W0hi | [256,512) W0lo | [512,1024) W1hi | [1024,1536) W1lo
// ============================================================================
__global__ __launch_bounds__(256) void prep_weights(const float* __restrict__ W0,
                                                    const float* __restrict__ W1,
                                                    uint4* __restrict__ ws) {
    const int tid = threadIdx.x;          // 0..255
    const int lane = tid & 63;
    const int m = lane & 15, q = lane >> 4;

    {   // W0^T: 4 n-tiles, 1 k-step. unit = tile*64+lane = tid.
        const int tile = tid >> 6;
        const int n = tile * 16 + m;
        uint32_t hi[4], lo[4];
        #pragma unroll
        for (int d = 0; d < 4; ++d) {
            const int k0 = q * 8 + 2 * d;
            split2(W0[k0 * 64 + n], W0[(k0 + 1) * 64 + n], hi[d], lo[d]);
        }
        ws[tid]       = make_uint4(hi[0], hi[1], hi[2], hi[3]);
        ws[256 + tid] = make_uint4(lo[0], lo[1], lo[2], lo[3]);
    }

    #pragma unroll
    for (int rep = 0; rep < 2; ++rep) {   // W1^T: 8 frags (nt*2+ks) x 64 lanes
        const int unit = tid + rep * 256;     // 0..511
        const int l2 = unit & 63, frag = unit >> 6;
        const int nt = frag >> 1, ks = frag & 1;
        const int mm = l2 & 15, qq = l2 >> 4;
        const int n = nt * 16 + mm;
        uint32_t hi[4], lo[4];
        #pragma unroll
        for (int d = 0; d < 4; ++d) {
            const int k0 = ks * 32 + qq * 8 + 2 * d;
            split2(W1[k0 * 64 + n], W1[(k0 + 1) * 64 + n], hi[d], lo[d]);
        }
        ws[512 + unit]  = make_uint4(hi[0], hi[1], hi[2], hi[3]);
        ws[1024 + unit] = make_uint4(lo[0], lo[1], lo[2], lo[3]);
    }
}

// ---- per-level hash-grid feature, runtime level constants (branchless) ----
static __device__ __forceinline__ float2 level_feat_rt(float x, float y, float fr,
                                                       int st /*res+1*/, bool dense,
                                                       const float* __restrict__ tb) {
    const float px = x * fr, py = y * fr;
    const float fx = floorf(px), fy = floorf(py);
    const float wx = px - fx, wy = py - fy;
    const int x0 = (int)fx, y0 = (int)fy;

    // dense candidates
    const int d00 = x0 + y0 * st;
    const int d01 = d00 + st;
    // hash candidates
    const unsigned a = (unsigned)x0, b = (unsigned)y0;
    const unsigned hb0 = b * PRIME_Y;
    const unsigned hb1 = hb0 + PRIME_Y;
    const int h00 = (int)((a ^ hb0) & TMASK);
    const int h01 = (int)((a ^ hb1) & TMASK);
    const int h10 = (int)(((a + 1u) ^ hb0) & TMASK);
    const int h11 = (int)(((a + 1u) ^ hb1) & TMASK);

    const int i00 = dense ? d00 : h00;
    const int i01 = dense ? d01 : h01;
    const int i10 = dense ? (d00 + 1) : h10;
    const int i11 = dense ? (d01 + 1) : h11;

    const float2 f00 = *(const float2*)(tb + 2 * (size_t)i00);
    const float2 f01 = *(const float2*)(tb + 2 * (size_t)i01);
    const float2 f10 = *(const float2*)(tb + 2 * (size_t)i10);
    const float2 f11 = *(const float2*)(tb + 2 * (size_t)i11);

    const float omx = 1.f - wx, omy = 1.f - wy;
    const float w00 = omx * omy, w01 = omx * wy, w10 = wx * omy, w11 = wx * wy;

    float2 e;
    e.x = f00.x * w00 + f01.x * w01 + f10.x * w10 + f11.x * w11;
    e.y = f00.y * w00 + f01.y * w01 + f10.y * w10 + f11.y * w11;
    return e;
}

// ============================================================================
// Main kernel. Block = 256 = 4 waves; each wave owns 64 points (4 tiles of 16).
// DIRECT-LAYOUT ENCODING (round-6 change): lane (q,m) encodes levels
// q*4..q*4+3 for points {t*16+m}, building MFMA B-fragments in registers --
// no enc LDS, no transpose, no enc bank conflicts. W1 frags staged in LDS per
// block (lane-consecutive b128 = conflict-free), read per n-tile.
// ============================================================================
__global__ __launch_bounds__(256, 3) void ngp_mfma(
    const float* __restrict__ xy,
    const float* __restrict__ tables,
    const float* __restrict__ W2,
    const uint4* __restrict__ ws,
    float* __restrict__ out)
{
    __shared__ uint4 w1LDS[1024];                       // 16384 B
    __shared__ alignas(16) uint32_t h0LDS[4 * 16 * 68]; // 17408 B
    __shared__ alignas(16) float w2t[3 * 64];           //   768 B

    const int tid = threadIdx.x;
    const int lane = tid & 63;
    const int wave = tid >> 6;
    const int m = lane & 15, q = lane >> 4;
    const int blockBase = blockIdx.x * 256;
    const int pbase = blockBase + wave * 64 + m;        // + t*16 per tile

    // ---- stage W1 frags + W2^T into LDS (coalesced) ----
    #pragma unroll
    for (int r = 0; r < 4; ++r) w1LDS[r * 256 + tid] = ws[512 + r * 256 + tid];
    if (tid < 192) w2t[(tid % 3) * 64 + (tid / 3)] = W2[tid];

    // ---- coords of this lane's 4 points (one per tile) ----
    float2 pc[4];
    #pragma unroll
    for (int t = 0; t < 4; ++t) pc[t] = ((const float2*)xy)[pbase + t * 16];

    // ---- W0 frags resident (32 VGPR, reused all 4 tiles) ----
    v8s w0h[4], w0l[4];
    #pragma unroll
    for (int t4 = 0; t4 < 4; ++t4) {
        w0h[t4] = __builtin_bit_cast(v8s, ws[t4 * 64 + lane]);
        w0l[t4] = __builtin_bit_cast(v8s, ws[256 + t4 * 64 + lane]);
    }

    // ---- per-lane level constants: this lane handles levels q*4+i ----
    constexpr float RESF[NLEV] = {16.f, 24.f, 36.f, 54.f, 81.f, 121.f, 182.f, 273.f,
                                  410.f, 615.f, 922.f, 1383.f, 2075.f, 3113.f, 4670.f, 7006.f};
    float frs[4]; int sts[4]; bool dns[4]; const float* tbs[4];
    #pragma unroll
    for (int i = 0; i < 4; ++i) {
        const float fAB = (q & 1) ? RESF[4 + i] : RESF[i];
        const float fCD = (q & 1) ? RESF[12 + i] : RESF[8 + i];
        const float f = (q & 2) ? fCD : fAB;
        frs[i] = f;
        sts[i] = (int)f + 1;
        // dense iff level <= 9  (levels 0..9 satisfy (res+1)^2 <= T)
        dns[i] = (i < 2) ? (q <= 2) : (q <= 1);
        tbs[i] = tables + ((size_t)(unsigned)(q * 4 + i) << 20);   // level * TBL*2
    }

    __syncthreads();   // w1LDS + w2t visibility

    #pragma unroll 1
    for (int t = 0; t < 4; ++t) {
        // ---- encode tile t directly into B-frag layout ----
        uint32_t ehd[4], eld[4];
        #pragma unroll
        for (int i = 0; i < 4; ++i) {
            const float2 e = level_feat_rt(pc[t].x, pc[t].y, frs[i], sts[i], dns[i], tbs[i]);
            split2(e.x, e.y, ehd[i], eld[i]);
        }
        const v8s eH = __builtin_bit_cast(v8s, make_uint4(ehd[0], ehd[1], ehd[2], ehd[3]));
        const v8s eL = __builtin_bit_cast(v8s, make_uint4(eld[0], eld[1], eld[2], eld[3]));

        // ---- L0: D0[n][p] = W0^T x enc^T, 3-term split ----
        v4f acc0[4];
        #pragma unroll
        for (int nt = 0; nt < 4; ++nt) {
            v4f c = {0.f, 0.f, 0.f, 0.f};
            c = __builtin_amdgcn_mfma_f32_16x16x32_bf16(w0l[nt], eH, c, 0, 0, 0);
            c = __builtin_amdgcn_mfma_f32_16x16x32_bf16(w0h[nt], eL, c, 0, 0, 0);
            c = __builtin_amdgcn_mfma_f32_16x16x32_bf16(w0h[nt], eH, c, 0, 0, 0);
            acc0[nt] = c;
        }

        // ---- relu + split h0 -> wave-local LDS bounce (C-layout -> B-layout)
        uint32_t* hrow = h0LDS + (wave * 16 + m) * 68;
        #pragma unroll
        for (int nt = 0; nt < 4; ++nt) {
            const float r0 = fmaxf(acc0[nt][0], 0.f), r1 = fmaxf(acc0[nt][1], 0.f);
            const float r2 = fmaxf(acc0[nt][2], 0.f), r3 = fmaxf(acc0[nt][3], 0.f);
            uint32_t h0w, l0w, h1w, l1w;
            split2(r0, r1, h0w, l0w);
            split2(r2, r3, h1w, l1w);
            *((uint2*)(hrow + nt * 8 + q * 2))      = make_uint2(h0w, h1w);
            *((uint2*)(hrow + 32 + nt * 8 + q * 2)) = make_uint2(l0w, l1w);
        }

        // ---- L1 B-frags ----
        const v8s b0H = __builtin_bit_cast(v8s, *((const uint4*)(hrow + q * 4)));
        const v8s b0L = __builtin_bit_cast(v8s, *((const uint4*)(hrow + 32 + q * 4)));
        const v8s b1H = __builtin_bit_cast(v8s, *((const uint4*)(hrow + 16 + q * 4)));
        const v8s b1L = __builtin_bit_cast(v8s, *((const uint4*)(hrow + 48 + q * 4)));

        // ---- L1 + L2 epilogue fused per n-tile (acc1 never materializes) ----
        float o0 = 0.f, o1 = 0.f, o2 = 0.f;
        #pragma unroll
        for (int nt = 0; nt < 4; ++nt) {
            const v8s a0h = __builtin_bit_cast(v8s, w1LDS[(nt * 2 + 0) * 64 + lane]);
            const v8s a0l = __builtin_bit_cast(v8s, w1LDS[512 + (nt * 2 + 0) * 64 + lane]);
            const v8s a1h = __builtin_bit_cast(v8s, w1LDS[(nt * 2 + 1) * 64 + lane]);
            const v8s a1l = __builtin_bit_cast(v8s, w1LDS[512 + (nt * 2 + 1) * 64 + lane]);
            v4f c = {0.f, 0.f, 0.f, 0.f};
            c = __builtin_amdgcn_mfma_f32_16x16x32_bf16(a0l, b0H, c, 0, 0, 0);
            c = __builtin_amdgcn_mfma_f32_16x16x32_bf16(a0h, b0L, c, 0, 0, 0);
            c = __builtin_amdgcn_mfma_f32_16x16x32_bf16(a0h, b0H, c, 0, 0, 0);
            c = __builtin_amdgcn_mfma_f32_16x16x32_bf16(a1l, b1H, c, 0, 0, 0);
            c = __builtin_amdgcn_mfma_f32_16x16x32_bf16(a1h, b1L, c, 0, 0, 0);
            c = __builtin_amdgcn_mfma_f32_16x16x32_bf16(a1h, b1H, c, 0, 0, 0);

            const int n = nt * 16 + q * 4;
            const float4 wa = *((const float4*)(w2t + 0 * 64 + n));
            const float4 wb = *((const float4*)(w2t + 1 * 64 + n));
            const float4 wc = *((const float4*)(w2t + 2 * 64 + n));
            const float h0r = fmaxf(c[0], 0.f), h1r = fmaxf(c[1], 0.f);
            const float h2r = fmaxf(c[2], 0.f), h3r = fmaxf(c[3], 0.f);
            o0 = fmaf(h0r, wa.x, fmaf(h1r, wa.y, fmaf(h2r, wa.z, fmaf(h3r, wa.w, o0))));
            o1 = fmaf(h0r, wb.x, fmaf(h1r, wb.y, fmaf(h2r, wb.z, fmaf(h3r, wb.w, o1))));
            o2 = fmaf(h0r, wc.x, fmaf(h1r, wc.y, fmaf(h2r, wc.z, fmaf(h3r, wc.w, o2))));
        }

        o0 += __shfl_xor(o0, 16); o0 += __shfl_xor(o0, 32);
        o1 += __shfl_xor(o1, 16); o1 += __shfl_xor(o1, 32);
        o2 += __shfl_xor(o2, 16); o2 += __shfl_xor(o2, 32);

        if (lane < 16) {
            const int p = blockBase + wave * 64 + t * 16 + lane;
            out[p] = o0;
            out[NPTS + p] = o1;
            out[2 * NPTS + p] = o2;
        }
    }
}

extern "C" void kernel_launch(void* const* d_in, const int* in_sizes, int n_in,
                              void* d_out, int out_size, void* d_ws, size_t ws_size,
                              hipStream_t stream) {
    const float* xy     = (const float*)d_in[0];
    const float* tables = (const float*)d_in[1];
    const float* W0     = (const float*)d_in[2];
    const float* W1     = (const float*)d_in[3];
    const float* W2     = (const float*)d_in[4];
    float* out = (float*)d_out;
    uint4* ws  = (uint4*)d_ws;   // 1536 x 16B = 24 KB

    hipLaunchKernelGGL(prep_weights, dim3(1), dim3(256), 0, stream, W0, W1, ws);
    hipLaunchKernelGGL(ngp_mfma, dim3(NPTS / 256), dim3(256), 0, stream,
                       xy, tables, W2, ws, out);
}

// Round 7
// 279.141 us; speedup vs baseline: 1.0062x; 1.0062x over previous
//
#include <hip/hip_runtime.h>
#include <cstdint>
#include <cstddef>

#define S_DIM 1024
#define NPTS (S_DIM * S_DIM)
#define NLEV 16
#define TBL (1u << 19)
#define TMASK (TBL - 1u)
#define PRIME_Y 2654435761u

typedef float v4f __attribute__((ext_vector_type(4)));
typedef short v8s __attribute__((ext_vector_type(8)));

// ---- split-bf16 helpers: x = hi + lo, both truncated bf16 ----
// pack two fp32 (a=even k, b=odd k) into one dword of 2 bf16 (a in low short).
__device__ __forceinline__ void split2(float a, float b, uint32_t& hi, uint32_t& lo) {
    uint32_t ua = __float_as_uint(a), ub = __float_as_uint(b);
    uint32_t ha = ua & 0xFFFF0000u, hb = ub & 0xFFFF0000u;
    float la = a - __uint_as_float(ha);
    float lb = b - __uint_as_float(hb);
    hi = (ha >> 16) | hb;
    lo = (__float_as_uint(la) >> 16) | (__float_as_uint(lb) & 0xFFFF0000u);
}

// ============================================================================
// Pre-pass (verified round 5): bf16 hi/lo A-fragments of W0^T (64x32) and
// W1^T (64x64), fragment-linear in d_ws.
// ws as uint4: [0,256) W0hi | [256,512) W0lo | [512,1024) W1hi | [1024,1536) W1lo
// ============================================================================
__global__ __launch_bounds__(256) void prep_weights(const float* __restrict__ W0,
                                                    const float* __restrict__ W1,
                                                    uint4* __restrict__ ws) {
    const int tid = threadIdx.x;          // 0..255
    const int lane = tid & 63;
    const int m = lane & 15, q = lane >> 4;

    {   // W0^T: 4 n-tiles, 1 k-step. unit = tile*64+lane = tid.
        const int tile = tid >> 6;
        const int n = tile * 16 + m;
        uint32_t hi[4], lo[4];
        #pragma unroll
        for (int d = 0; d < 4; ++d) {
            const int k0 = q * 8 + 2 * d;
            split2(W0[k0 * 64 + n], W0[(k0 + 1) * 64 + n], hi[d], lo[d]);
        }
        ws[tid]       = make_uint4(hi[0], hi[1], hi[2], hi[3]);
        ws[256 + tid] = make_uint4(lo[0], lo[1], lo[2], lo[3]);
    }

    #pragma unroll
    for (int rep = 0; rep < 2; ++rep) {   // W1^T: 8 frags (nt*2+ks) x 64 lanes
        const int unit = tid + rep * 256;     // 0..511
        const int l2 = unit & 63, frag = unit >> 6;
        const int nt = frag >> 1, ks = frag & 1;
        const int mm = l2 & 15, qq = l2 >> 4;
        const int n = nt * 16 + mm;
        uint32_t hi[4], lo[4];
        #pragma unroll
        for (int d = 0; d < 4; ++d) {
            const int k0 = ks * 32 + qq * 8 + 2 * d;
            split2(W1[k0 * 64 + n], W1[(k0 + 1) * 64 + n], hi[d], lo[d]);
        }
        ws[512 + unit]  = make_uint4(hi[0], hi[1], hi[2], hi[3]);
        ws[1024 + unit] = make_uint4(lo[0], lo[1], lo[2], lo[3]);
    }
}

// ---- per-level hash-grid feature, runtime level constants (branchless) ----
static __device__ __forceinline__ float2 level_feat_rt(float x, float y, float fr,
                                                       int st /*res+1*/, bool dense,
                                                       const float* __restrict__ tb) {
    const float px = x * fr, py = y * fr;
    const float fx = floorf(px), fy = floorf(py);
    const float wx = px - fx, wy = py - fy;
    const int x0 = (int)fx, y0 = (int)fy;

    const int d00 = x0 + y0 * st;
    const int d01 = d00 + st;
    const unsigned a = (unsigned)x0, b = (unsigned)y0;
    const unsigned hb0 = b * PRIME_Y;
    const unsigned hb1 = hb0 + PRIME_Y;
    const int h00 = (int)((a ^ hb0) & TMASK);
    const int h01 = (int)((a ^ hb1) & TMASK);
    const int h10 = (int)(((a + 1u) ^ hb0) & TMASK);
    const int h11 = (int)(((a + 1u) ^ hb1) & TMASK);

    const int i00 = dense ? d00 : h00;
    const int i01 = dense ? d01 : h01;
    const int i10 = dense ? (d00 + 1) : h10;
    const int i11 = dense ? (d01 + 1) : h11;

    const float2 f00 = *(const float2*)(tb + 2 * (size_t)i00);
    const float2 f01 = *(const float2*)(tb + 2 * (size_t)i01);
    const float2 f10 = *(const float2*)(tb + 2 * (size_t)i10);
    const float2 f11 = *(const float2*)(tb + 2 * (size_t)i11);

    const float omx = 1.f - wx, omy = 1.f - wy;
    const float w00 = omx * omy, w01 = omx * wy, w10 = wx * omy, w11 = wx * wy;

    float2 e;
    e.x = f00.x * w00 + f01.x * w01 + f10.x * w10 + f11.x * w11;
    e.y = f00.y * w00 + f01.y * w01 + f10.y * w10 + f11.y * w11;
    return e;
}

// ============================================================================
// Main kernel. Block = 256 = 4 waves; each wave owns 64 points (4 tiles of 16).
// Direct-layout encoding: lane (q,m) encodes levels q*4..q*4+3 for points
// {t*16+m}, building MFMA B-fragments in registers (no enc LDS/transpose).
// ROUND-7 FIX: zero locals indexed by the runtime t -- point coords reloaded
// inside the loop; level constants are named scalars (round-6 spilled 180 MB
// via pc[t]/frs[]/tbs[] alloca demotion).
// ============================================================================
__global__ __launch_bounds__(256, 3) void ngp_mfma(
    const float* __restrict__ xy,
    const float* __restrict__ tables,
    const float* __restrict__ W2,
    const uint4* __restrict__ ws,
    float* __restrict__ out)
{
    __shared__ uint4 w1LDS[1024];                       // 16384 B
    __shared__ alignas(16) uint32_t h0LDS[4 * 16 * 68]; // 17408 B
    __shared__ alignas(16) float w2t[3 * 64];           //   768 B

    const int tid = threadIdx.x;
    const int lane = tid & 63;
    const int wave = tid >> 6;
    const int m = lane & 15, q = lane >> 4;
    const int blockBase = blockIdx.x * 256;
    const int pbase = blockBase + wave * 64 + m;        // + t*16 per tile

    // ---- stage W1 frags + W2^T into LDS (coalesced) ----
    #pragma unroll
    for (int r = 0; r < 4; ++r) w1LDS[r * 256 + tid] = ws[512 + r * 256 + tid];
    if (tid < 192) w2t[(tid % 3) * 64 + (tid / 3)] = W2[tid];

    // ---- W0 frags resident (32 VGPR, reused all 4 tiles) ----
    v8s w0h[4], w0l[4];
    #pragma unroll
    for (int t4 = 0; t4 < 4; ++t4) {
        w0h[t4] = __builtin_bit_cast(v8s, ws[t4 * 64 + lane]);
        w0l[t4] = __builtin_bit_cast(v8s, ws[256 + t4 * 64 + lane]);
    }

    // ---- per-lane level constants: NAMED SCALARS (never an alloca) ----
    constexpr float RESF[NLEV] = {16.f, 24.f, 36.f, 54.f, 81.f, 121.f, 182.f, 273.f,
                                  410.f, 615.f, 922.f, 1383.f, 2075.f, 3113.f, 4670.f, 7006.f};
#define LVLF(i) ((q & 2) ? ((q & 1) ? RESF[12 + (i)] : RESF[8 + (i)]) \
                         : ((q & 1) ? RESF[4 + (i)]  : RESF[(i)]))
    const float fr0 = LVLF(0), fr1 = LVLF(1), fr2 = LVLF(2), fr3 = LVLF(3);
#undef LVLF
    const int st0 = (int)fr0 + 1, st1 = (int)fr1 + 1;
    const int st2 = (int)fr2 + 1, st3 = (int)fr3 + 1;
    // dense iff level <= 9; level = q*4 + i
    const bool dn0 = (q <= 2), dn1 = (q <= 2), dn2 = (q <= 1), dn3 = (q <= 1);
    const float* tb0 = tables + ((size_t)(unsigned)(q * 4 + 0) << 20);
    const float* tb1 = tables + ((size_t)(unsigned)(q * 4 + 1) << 20);
    const float* tb2 = tables + ((size_t)(unsigned)(q * 4 + 2) << 20);
    const float* tb3 = tables + ((size_t)(unsigned)(q * 4 + 3) << 20);

    __syncthreads();   // w1LDS + w2t visibility

    #pragma unroll 1
    for (int t = 0; t < 4; ++t) {
        // ---- encode tile t directly into B-frag layout ----
        const float2 p = ((const float2*)xy)[pbase + t * 16];
        const float2 e0 = level_feat_rt(p.x, p.y, fr0, st0, dn0, tb0);
        const float2 e1 = level_feat_rt(p.x, p.y, fr1, st1, dn1, tb1);
        const float2 e2 = level_feat_rt(p.x, p.y, fr2, st2, dn2, tb2);
        const float2 e3 = level_feat_rt(p.x, p.y, fr3, st3, dn3, tb3);
        uint32_t eh0, el0, eh1, el1, eh2, el2, eh3, el3;
        split2(e0.x, e0.y, eh0, el0);
        split2(e1.x, e1.y, eh1, el1);
        split2(e2.x, e2.y, eh2, el2);
        split2(e3.x, e3.y, eh3, el3);
        const v8s eH = __builtin_bit_cast(v8s, make_uint4(eh0, eh1, eh2, eh3));
        const v8s eL = __builtin_bit_cast(v8s, make_uint4(el0, el1, el2, el3));

        // ---- L0: D0[n][p] = W0^T x enc^T, 3-term split ----
        v4f acc0[4];
        #pragma unroll
        for (int nt = 0; nt < 4; ++nt) {
            v4f c = {0.f, 0.f, 0.f, 0.f};
            c = __builtin_amdgcn_mfma_f32_16x16x32_bf16(w0l[nt], eH, c, 0, 0, 0);
            c = __builtin_amdgcn_mfma_f32_16x16x32_bf16(w0h[nt], eL, c, 0, 0, 0);
            c = __builtin_amdgcn_mfma_f32_16x16x32_bf16(w0h[nt], eH, c, 0, 0, 0);
            acc0[nt] = c;
        }

        // ---- relu + split h0 -> wave-local LDS bounce (C-layout -> B-layout)
        uint32_t* hrow = h0LDS + (wave * 16 + m) * 68;
        #pragma unroll
        for (int nt = 0; nt < 4; ++nt) {
            const float r0 = fmaxf(acc0[nt][0], 0.f), r1 = fmaxf(acc0[nt][1], 0.f);
            const float r2 = fmaxf(acc0[nt][2], 0.f), r3 = fmaxf(acc0[nt][3], 0.f);
            uint32_t h0w, l0w, h1w, l1w;
            split2(r0, r1, h0w, l0w);
            split2(r2, r3, h1w, l1w);
            *((uint2*)(hrow + nt * 8 + q * 2))      = make_uint2(h0w, h1w);
            *((uint2*)(hrow + 32 + nt * 8 + q * 2)) = make_uint2(l0w, l1w);
        }

        // ---- L1 B-frags ----
        const v8s b0H = __builtin_bit_cast(v8s, *((const uint4*)(hrow + q * 4)));
        const v8s b0L = __builtin_bit_cast(v8s, *((const uint4*)(hrow + 32 + q * 4)));
        const v8s b1H = __builtin_bit_cast(v8s, *((const uint4*)(hrow + 16 + q * 4)));
        const v8s b1L = __builtin_bit_cast(v8s, *((const uint4*)(hrow + 48 + q * 4)));

        // ---- L1 + L2 epilogue fused per n-tile (acc1 never materializes) ----
        float o0 = 0.f, o1 = 0.f, o2 = 0.f;
        #pragma unroll
        for (int nt = 0; nt < 4; ++nt) {
            const v8s a0h = __builtin_bit_cast(v8s, w1LDS[(nt * 2 + 0) * 64 + lane]);
            const v8s a0l = __builtin_bit_cast(v8s, w1LDS[512 + (nt * 2 + 0) * 64 + lane]);
            const v8s a1h = __builtin_bit_cast(v8s, w1LDS[(nt * 2 + 1) * 64 + lane]);
            const v8s a1l = __builtin_bit_cast(v8s, w1LDS[512 + (nt * 2 + 1) * 64 + lane]);
            v4f c = {0.f, 0.f, 0.f, 0.f};
            c = __builtin_amdgcn_mfma_f32_16x16x32_bf16(a0l, b0H, c, 0, 0, 0);
            c = __builtin_amdgcn_mfma_f32_16x16x32_bf16(a0h, b0L, c, 0, 0, 0);
            c = __builtin_amdgcn_mfma_f32_16x16x32_bf16(a0h, b0H, c, 0, 0, 0);
            c = __builtin_amdgcn_mfma_f32_16x16x32_bf16(a1l, b1H, c, 0, 0, 0);
            c = __builtin_amdgcn_mfma_f32_16x16x32_bf16(a1h, b1L, c, 0, 0, 0);
            c = __builtin_amdgcn_mfma_f32_16x16x32_bf16(a1h, b1H, c, 0, 0, 0);

            const int n = nt * 16 + q * 4;
            const float4 wa = *((const float4*)(w2t + 0 * 64 + n));
            const float4 wb = *((const float4*)(w2t + 1 * 64 + n));
            const float4 wc = *((const float4*)(w2t + 2 * 64 + n));
            const float h0r = fmaxf(c[0], 0.f), h1r = fmaxf(c[1], 0.f);
            const float h2r = fmaxf(c[2], 0.f), h3r = fmaxf(c[3], 0.f);
            o0 = fmaf(h0r, wa.x, fmaf(h1r, wa.y, fmaf(h2r, wa.z, fmaf(h3r, wa.w, o0))));
            o1 = fmaf(h0r, wb.x, fmaf(h1r, wb.y, fmaf(h2r, wb.z, fmaf(h3r, wb.w, o1))));
            o2 = fmaf(h0r, wc.x, fmaf(h1r, wc.y, fmaf(h2r, wc.z, fmaf(h3r, wc.w, o2))));
        }

        o0 += __shfl_xor(o0, 16); o0 += __shfl_xor(o0, 32);
        o1 += __shfl_xor(o1, 16); o1 += __shfl_xor(o1, 32);
        o2 += __shfl_xor(o2, 16); o2 += __shfl_xor(o2, 32);

        if (lane < 16) {
            const int pidx = blockBase + wave * 64 + t * 16 + lane;
            out[pidx] = o0;
            out[NPTS + pidx] = o1;
            out[2 * NPTS + pidx] = o2;
        }
    }
}

extern "C" void kernel_launch(void* const* d_in, const int* in_sizes, int n_in,
                              void* d_out, int out_size, void* d_ws, size_t ws_size,
                              hipStream_t stream) {
    const float* xy     = (const float*)d_in[0];
    const float* tables = (const float*)d_in[1];
    const float* W0     = (const float*)d_in[2];
    const float* W1     = (const float*)d_in[3];
    const float* W2     = (const float*)d_in[4];
    float* out = (float*)d_out;
    uint4* ws  = (uint4*)d_ws;   // 1536 x 16B = 24 KB

    hipLaunchKernelGGL(prep_weights, dim3(1), dim3(256), 0, stream, W0, W1, ws);
    hipLaunchKernelGGL(ngp_mfma, dim3(NPTS / 256), dim3(256), 0, stream,
                       xy, tables, W2, ws, out);
}

// Round 8
// 186.534 us; speedup vs baseline: 1.5058x; 1.4965x over previous
//
#include <hip/hip_runtime.h>
#include <cstdint>
#include <cstddef>

#define S_DIM 1024
#define NPTS (S_DIM * S_DIM)
#define NLEV 16
#define TBL (1u << 19)
#define TMASK (TBL - 1u)
#define PRIME_Y 2654435761u

typedef float v4f __attribute__((ext_vector_type(4)));
typedef short v8s __attribute__((ext_vector_type(8)));

// ---- split-bf16 helpers: x = hi + lo, both truncated bf16 ----
// pack two fp32 (a=even k, b=odd k) into one dword of 2 bf16 (a in low short).
__device__ __forceinline__ void split2(float a, float b, uint32_t& hi, uint32_t& lo) {
    uint32_t ua = __float_as_uint(a), ub = __float_as_uint(b);
    uint32_t ha = ua & 0xFFFF0000u, hb = ub & 0xFFFF0000u;
    float la = a - __uint_as_float(ha);
    float lb = b - __uint_as_float(hb);
    hi = (ha >> 16) | hb;
    lo = (__float_as_uint(la) >> 16) | (__float_as_uint(lb) & 0xFFFF0000u);
}

// ============================================================================
// Pre-pass (verified round 5): bf16 hi/lo A-fragments of W0^T (64x32) and
// W1^T (64x64), fragment-linear in d_ws.
// ws as uint4: [0,256) W0hi | [256,512) W0lo | [512,1024) W1hi | [1024,1536) W1lo
// ============================================================================
__global__ __launch_bounds__(256) void prep_weights(const float* __restrict__ W0,
                                                    const float* __restrict__ W1,
                                                    uint4* __restrict__ ws) {
    const int tid = threadIdx.x;          // 0..255
    const int lane = tid & 63;
    const int m = lane & 15, q = lane >> 4;

    {   // W0^T: 4 n-tiles, 1 k-step. unit = tile*64+lane = tid.
        const int tile = tid >> 6;
        const int n = tile * 16 + m;
        uint32_t hi[4], lo[4];
        #pragma unroll
        for (int d = 0; d < 4; ++d) {
            const int k0 = q * 8 + 2 * d;
            split2(W0[k0 * 64 + n], W0[(k0 + 1) * 64 + n], hi[d], lo[d]);
        }
        ws[tid]       = make_uint4(hi[0], hi[1], hi[2], hi[3]);
        ws[256 + tid] = make_uint4(lo[0], lo[1], lo[2], lo[3]);
    }

    #pragma unroll
    for (int rep = 0; rep < 2; ++rep) {   // W1^T: 8 frags (nt*2+ks) x 64 lanes
        const int unit = tid + rep * 256;     // 0..511
        const int l2 = unit & 63, frag = unit >> 6;
        const int nt = frag >> 1, ks = frag & 1;
        const int mm = l2 & 15, qq = l2 >> 4;
        const int n = nt * 16 + mm;
        uint32_t hi[4], lo[4];
        #pragma unroll
        for (int d = 0; d < 4; ++d) {
            const int k0 = ks * 32 + qq * 8 + 2 * d;
            split2(W1[k0 * 64 + n], W1[(k0 + 1) * 64 + n], hi[d], lo[d]);
        }
        ws[512 + unit]  = make_uint4(hi[0], hi[1], hi[2], hi[3]);
        ws[1024 + unit] = make_uint4(lo[0], lo[1], lo[2], lo[3]);
    }
}

// ---- per-level hash-grid feature, runtime level constants (branchless) ----
static __device__ __forceinline__ float2 level_feat_rt(float x, float y, float fr,
                                                       int st /*res+1*/, bool dense,
                                                       const float* __restrict__ tb) {
    const float px = x * fr, py = y * fr;
    const float fx = floorf(px), fy = floorf(py);
    const float wx = px - fx, wy = py - fy;
    const int x0 = (int)fx, y0 = (int)fy;

    const int d00 = x0 + y0 * st;
    const int d01 = d00 + st;
    const unsigned a = (unsigned)x0, b = (unsigned)y0;
    const unsigned hb0 = b * PRIME_Y;
    const unsigned hb1 = hb0 + PRIME_Y;
    const int h00 = (int)((a ^ hb0) & TMASK);
    const int h01 = (int)((a ^ hb1) & TMASK);
    const int h10 = (int)(((a + 1u) ^ hb0) & TMASK);
    const int h11 = (int)(((a + 1u) ^ hb1) & TMASK);

    const int i00 = dense ? d00 : h00;
    const int i01 = dense ? d01 : h01;
    const int i10 = dense ? (d00 + 1) : h10;
    const int i11 = dense ? (d01 + 1) : h11;

    const float2 f00 = *(const float2*)(tb + 2 * (size_t)i00);
    const float2 f01 = *(const float2*)(tb + 2 * (size_t)i01);
    const float2 f10 = *(const float2*)(tb + 2 * (size_t)i10);
    const float2 f11 = *(const float2*)(tb + 2 * (size_t)i11);

    const float omx = 1.f - wx, omy = 1.f - wy;
    const float w00 = omx * omy, w01 = omx * wy, w10 = wx * omy, w11 = wx * wy;

    float2 e;
    e.x = f00.x * w00 + f01.x * w01 + f10.x * w10 + f11.x * w11;
    e.y = f00.y * w00 + f01.y * w01 + f10.y * w10 + f11.y * w11;
    return e;
}

// ============================================================================
// Main kernel. Block = 256 = 4 waves; each wave owns 64 points (4 tiles of 16).
// Direct-layout encoding: lane (q,m) encodes levels q*4..q*4+3 for points
// {t*16+m}, building MFMA B-fragments in registers (no enc LDS/transpose).
// ROUND-8 FIX: __launch_bounds__(256, 2). gfx950's unified VGPR/AGPR file
// means (256,3) caps TOTAL regs at ~168/wave; with MFMA accumulators in
// AGPRs the arch-VGPR share fell to 84 and the allocator spilled ~35 dwords
// per thread across the t-loop (rounds 6/7: 148-180 MB scratch writes).
// (256,2) restores the 256-reg budget that rounds 4/5 ran spill-free.
// ============================================================================
__global__ __launch_bounds__(256, 2) void ngp_mfma(
    const float* __restrict__ xy,
    const float* __restrict__ tables,
    const float* __restrict__ W2,
    const uint4* __restrict__ ws,
    float* __restrict__ out)
{
    __shared__ uint4 w1LDS[1024];                       // 16384 B
    __shared__ alignas(16) uint32_t h0LDS[4 * 16 * 68]; // 17408 B
    __shared__ alignas(16) float w2t[3 * 64];           //   768 B

    const int tid = threadIdx.x;
    const int lane = tid & 63;
    const int wave = tid >> 6;
    const int m = lane & 15, q = lane >> 4;
    const int blockBase = blockIdx.x * 256;
    const int pbase = blockBase + wave * 64 + m;        // + t*16 per tile

    // ---- stage W1 frags + W2^T into LDS (coalesced) ----
    #pragma unroll
    for (int r = 0; r < 4; ++r) w1LDS[r * 256 + tid] = ws[512 + r * 256 + tid];
    if (tid < 192) w2t[(tid % 3) * 64 + (tid / 3)] = W2[tid];

    // ---- W0 frags resident (32 VGPR, reused all 4 tiles) ----
    v8s w0h[4], w0l[4];
    #pragma unroll
    for (int t4 = 0; t4 < 4; ++t4) {
        w0h[t4] = __builtin_bit_cast(v8s, ws[t4 * 64 + lane]);
        w0l[t4] = __builtin_bit_cast(v8s, ws[256 + t4 * 64 + lane]);
    }

    // ---- per-lane level constants: NAMED SCALARS (never an alloca) ----
    constexpr float RESF[NLEV] = {16.f, 24.f, 36.f, 54.f, 81.f, 121.f, 182.f, 273.f,
                                  410.f, 615.f, 922.f, 1383.f, 2075.f, 3113.f, 4670.f, 7006.f};
#define LVLF(i) ((q & 2) ? ((q & 1) ? RESF[12 + (i)] : RESF[8 + (i)]) \
                         : ((q & 1) ? RESF[4 + (i)]  : RESF[(i)]))
    const float fr0 = LVLF(0), fr1 = LVLF(1), fr2 = LVLF(2), fr3 = LVLF(3);
#undef LVLF
    const int st0 = (int)fr0 + 1, st1 = (int)fr1 + 1;
    const int st2 = (int)fr2 + 1, st3 = (int)fr3 + 1;
    // dense iff level <= 9; level = q*4 + i
    const bool dn0 = (q <= 2), dn1 = (q <= 2), dn2 = (q <= 1), dn3 = (q <= 1);
    const float* tb0 = tables + ((size_t)(unsigned)(q * 4 + 0) << 20);
    const float* tb1 = tables + ((size_t)(unsigned)(q * 4 + 1) << 20);
    const float* tb2 = tables + ((size_t)(unsigned)(q * 4 + 2) << 20);
    const float* tb3 = tables + ((size_t)(unsigned)(q * 4 + 3) << 20);

    __syncthreads();   // w1LDS + w2t visibility

    #pragma unroll 1
    for (int t = 0; t < 4; ++t) {
        // ---- encode tile t directly into B-frag layout ----
        const float2 p = ((const float2*)xy)[pbase + t * 16];
        const float2 e0 = level_feat_rt(p.x, p.y, fr0, st0, dn0, tb0);
        const float2 e1 = level_feat_rt(p.x, p.y, fr1, st1, dn1, tb1);
        const float2 e2 = level_feat_rt(p.x, p.y, fr2, st2, dn2, tb2);
        const float2 e3 = level_feat_rt(p.x, p.y, fr3, st3, dn3, tb3);
        uint32_t eh0, el0, eh1, el1, eh2, el2, eh3, el3;
        split2(e0.x, e0.y, eh0, el0);
        split2(e1.x, e1.y, eh1, el1);
        split2(e2.x, e2.y, eh2, el2);
        split2(e3.x, e3.y, eh3, el3);
        const v8s eH = __builtin_bit_cast(v8s, make_uint4(eh0, eh1, eh2, eh3));
        const v8s eL = __builtin_bit_cast(v8s, make_uint4(el0, el1, el2, el3));

        // ---- L0: D0[n][p] = W0^T x enc^T, 3-term split ----
        v4f acc0[4];
        #pragma unroll
        for (int nt = 0; nt < 4; ++nt) {
            v4f c = {0.f, 0.f, 0.f, 0.f};
            c = __builtin_amdgcn_mfma_f32_16x16x32_bf16(w0l[nt], eH, c, 0, 0, 0);
            c = __builtin_amdgcn_mfma_f32_16x16x32_bf16(w0h[nt], eL, c, 0, 0, 0);
            c = __builtin_amdgcn_mfma_f32_16x16x32_bf16(w0h[nt], eH, c, 0, 0, 0);
            acc0[nt] = c;
        }

        // ---- relu + split h0 -> wave-local LDS bounce (C-layout -> B-layout)
        uint32_t* hrow = h0LDS + (wave * 16 + m) * 68;
        #pragma unroll
        for (int nt = 0; nt < 4; ++nt) {
            const float r0 = fmaxf(acc0[nt][0], 0.f), r1 = fmaxf(acc0[nt][1], 0.f);
            const float r2 = fmaxf(acc0[nt][2], 0.f), r3 = fmaxf(acc0[nt][3], 0.f);
            uint32_t h0w, l0w, h1w, l1w;
            split2(r0, r1, h0w, l0w);
            split2(r2, r3, h1w, l1w);
            *((uint2*)(hrow + nt * 8 + q * 2))      = make_uint2(h0w, h1w);
            *((uint2*)(hrow + 32 + nt * 8 + q * 2)) = make_uint2(l0w, l1w);
        }

        // ---- L1 B-frags ----
        const v8s b0H = __builtin_bit_cast(v8s, *((const uint4*)(hrow + q * 4)));
        const v8s b0L = __builtin_bit_cast(v8s, *((const uint4*)(hrow + 32 + q * 4)));
        const v8s b1H = __builtin_bit_cast(v8s, *((const uint4*)(hrow + 16 + q * 4)));
        const v8s b1L = __builtin_bit_cast(v8s, *((const uint4*)(hrow + 48 + q * 4)));

        // ---- L1 + L2 epilogue fused per n-tile (acc1 never materializes) ----
        float o0 = 0.f, o1 = 0.f, o2 = 0.f;
        #pragma unroll
        for (int nt = 0; nt < 4; ++nt) {
            const v8s a0h = __builtin_bit_cast(v8s, w1LDS[(nt * 2 + 0) * 64 + lane]);
            const v8s a0l = __builtin_bit_cast(v8s, w1LDS[512 + (nt * 2 + 0) * 64 + lane]);
            const v8s a1h = __builtin_bit_cast(v8s, w1LDS[(nt * 2 + 1) * 64 + lane]);
            const v8s a1l = __builtin_bit_cast(v8s, w1LDS[512 + (nt * 2 + 1) * 64 + lane]);
            v4f c = {0.f, 0.f, 0.f, 0.f};
            c = __builtin_amdgcn_mfma_f32_16x16x32_bf16(a0l, b0H, c, 0, 0, 0);
            c = __builtin_amdgcn_mfma_f32_16x16x32_bf16(a0h, b0L, c, 0, 0, 0);
            c = __builtin_amdgcn_mfma_f32_16x16x32_bf16(a0h, b0H, c, 0, 0, 0);
            c = __builtin_amdgcn_mfma_f32_16x16x32_bf16(a1l, b1H, c, 0, 0, 0);
            c = __builtin_amdgcn_mfma_f32_16x16x32_bf16(a1h, b1L, c, 0, 0, 0);
            c = __builtin_amdgcn_mfma_f32_16x16x32_bf16(a1h, b1H, c, 0, 0, 0);

            const int n = nt * 16 + q * 4;
            const float4 wa = *((const float4*)(w2t + 0 * 64 + n));
            const float4 wb = *((const float4*)(w2t + 1 * 64 + n));
            const float4 wc = *((const float4*)(w2t + 2 * 64 + n));
            const float h0r = fmaxf(c[0], 0.f), h1r = fmaxf(c[1], 0.f);
            const float h2r = fmaxf(c[2], 0.f), h3r = fmaxf(c[3], 0.f);
            o0 = fmaf(h0r, wa.x, fmaf(h1r, wa.y, fmaf(h2r, wa.z, fmaf(h3r, wa.w, o0))));
            o1 = fmaf(h0r, wb.x, fmaf(h1r, wb.y, fmaf(h2r, wb.z, fmaf(h3r, wb.w, o1))));
            o2 = fmaf(h0r, wc.x, fmaf(h1r, wc.y, fmaf(h2r, wc.z, fmaf(h3r, wc.w, o2))));
        }

        o0 += __shfl_xor(o0, 16); o0 += __shfl_xor(o0, 32);
        o1 += __shfl_xor(o1, 16); o1 += __shfl_xor(o1, 32);
        o2 += __shfl_xor(o2, 16); o2 += __shfl_xor(o2, 32);

        if (lane < 16) {
            const int pidx = blockBase + wave * 64 + t * 16 + lane;
            out[pidx] = o0;
            out[NPTS + pidx] = o1;
            out[2 * NPTS + pidx] = o2;
        }
    }
}

extern "C" void kernel_launch(void* const* d_in, const int* in_sizes, int n_in,
                              void* d_out, int out_size, void* d_ws, size_t ws_size,
                              hipStream_t stream) {
    const float* xy     = (const float*)d_in[0];
    const float* tables = (const float*)d_in[1];
    const float* W0     = (const float*)d_in[2];
    const float* W1     = (const float*)d_in[3];
    const float* W2     = (const float*)d_in[4];
    float* out = (float*)d_out;
    uint4* ws  = (uint4*)d_ws;   // 1536 x 16B = 24 KB

    hipLaunchKernelGGL(prep_weights, dim3(1), dim3(256), 0, stream, W0, W1, ws);
    hipLaunchKernelGGL(ngp_mfma, dim3(NPTS / 256), dim3(256), 0, stream,
                       xy, tables, W2, ws, out);
}